// Round 5
// baseline (470.470 us; speedup 1.0000x reference)
//
#include <hip/hip_runtime.h>
#include <math.h>

// Masked attention fwd, B=8, Sq=Sk=2048, D=128, fp32 in/out.
// Flash-attention, swapped QK^T (S^T = K*Q^T) so P stays in-lane for PV.
// bf16 hi/lo split MFMA (3 mfma per product => ~fp32 accuracy).
// 4-way KV split: 2 in-block groups (LDS merge) x 2 across blocks (ws merge).
// Single-buffered 64KB LDS -> 2 blocks/CU -> 16 waves/CU.

typedef short bf16x8 __attribute__((ext_vector_type(8)));
typedef short short4v __attribute__((ext_vector_type(4)));
typedef float f32x4 __attribute__((ext_vector_type(4)));

#define MFMA16 __builtin_amdgcn_mfma_f32_16x16x32_bf16

namespace {
constexpr int SKn = 2048, DH = 128;
constexpr int QB = 64;
constexpr int ROWS = 8 * 2048;              // 16384 total q rows
constexpr size_t OPART_BYTES = 2ull * ROWS * DH * 4;   // 16 MiB
constexpr size_t ML_BYTES = 2ull * ROWS * 8;           // 256 KiB
constexpr size_t WS_NEED = OPART_BYTES + ML_BYTES;

__device__ __forceinline__ unsigned short f2bf(float f) {   // RNE (prologue only)
    union { float f; unsigned u; } x; x.f = f;
    unsigned r = x.u + 0x7FFFu + ((x.u >> 16) & 1u);
    return (unsigned short)(r >> 16);
}
__device__ __forceinline__ float bf2f(unsigned short h) {
    union { unsigned u; float f; } x; x.u = ((unsigned)h) << 16;
    return x.f;
}
}  // namespace

// LDS map: group g2 at g2*32768 (single buffer):
//   Khi +0      [32 kv][128 d] bf16, 256B rows, swz: col ^ ((kv&15)<<4)
//   Klo +8192
//   Vhi +16384  [128 d][32 kv] bf16, 64B rows,  swz: col ^ ((d&7)<<3)
//   Vlo +24576
// Epilogue merge scratch (reused): O1 at wq*8448 (16x528B), ml at 33792+wq*128
__global__ __launch_bounds__(512, 4) void fattn_kernel(
    const float* __restrict__ Q, const float* __restrict__ K,
    const float* __restrict__ V, const float* __restrict__ M,
    float* __restrict__ Oout, float2* __restrict__ MLout, const int nkvh)
{
    __shared__ __align__(16) char smem[65536];
    const int bid = blockIdx.x;
    const int b  = bid & 7;          // batch per XCD for K/V L2 locality
    const int rest = bid >> 3;
    const int kvh = rest % nkvh;     // cross-block kv half
    const int qt = rest / nkvh;
    const int nstep = 16 * (2 / nkvh) * 2 / 2;   // nkvh=2 -> 16, nkvh=1 -> 32
    const int tid = threadIdx.x;
    const int lane = tid & 63;
    const int w = tid >> 6;          // 0..7
    const int g2 = w >> 2;           // in-block kv group 0/1
    const int wq = w & 3;            // q sub-tile, rows wq*16..+15
    const int gtid = tid & 255;
    const int m16 = lane & 15;
    const int g = lane >> 4;

    char* slotbase = smem + g2 * 32768;

    const int rowglobal = b * 2048 + qt * QB + wq * 16;
    const float* Qw = Q + (size_t)rowglobal * DH;
    const float* Kb = K + (size_t)b * SKn * DH;
    const float* Vb = V + (size_t)b * SKn * DH;
    const float* Mrow = M + (size_t)rowglobal * SKn + (size_t)m16 * SKn;
    float* Orow = Oout + ((size_t)kvh * ROWS + rowglobal) * DH;

    // ---- Q fragments (B-operand of S^T: lane(g,m16) holds Q[m16][c*32+g*8+e]) ----
    bf16x8 qh[4], ql[4];
#pragma unroll
    for (int c = 0; c < 4; ++c) {
        const float* qp = Qw + m16 * DH + c * 32 + g * 8;
        f32x4 a0 = *(const f32x4*)qp;
        f32x4 a1 = *(const f32x4*)(qp + 4);
#pragma unroll
        for (int j = 0; j < 8; ++j) {
            float x = (j < 4) ? a0[j] : a1[j - 4];
            unsigned short h = f2bf(x);
            qh[c][j] = (short)h;
            ql[c][j] = (short)f2bf(x - bf2f(h));
        }
    }

    f32x4 kreg[4], vreg[4];
    const int krow = gtid >> 5, kc4 = gtid & 31;   // K stage: coalesced
    const int vkv = gtid & 31,  vc8 = gtid >> 5;   // V stage: row-strided

    auto kv_of = [&](int t) { return kvh * 1024 + (2 * t + g2) * 32; };

    auto stage_load = [&](int t) {
        const int kv0 = kv_of(t);
#pragma unroll
        for (int i = 0; i < 4; ++i)
            kreg[i] = *(const f32x4*)(Kb + (size_t)(kv0 + i * 8 + krow) * DH + kc4 * 4);
#pragma unroll
        for (int i = 0; i < 4; ++i)
            vreg[i] = *(const f32x4*)(Vb + (size_t)(kv0 + vkv) * DH + (vc8 + i * 8) * 4);
    };

    // truncation hi/lo split + v_perm packing (hot path)
    auto stage_write = [&]() {
        char* Khi = slotbase;
        char* Klo = slotbase + 8192;
        char* Vhi = slotbase + 16384;
        char* Vlo = slotbase + 24576;
#pragma unroll
        for (int i = 0; i < 4; ++i) {
            const int row = i * 8 + krow;
            const unsigned b0 = __float_as_uint(kreg[i][0]);
            const unsigned b1 = __float_as_uint(kreg[i][1]);
            const unsigned b2 = __float_as_uint(kreg[i][2]);
            const unsigned b3 = __float_as_uint(kreg[i][3]);
            const float r0 = kreg[i][0] - __uint_as_float(b0 & 0xFFFF0000u);
            const float r1 = kreg[i][1] - __uint_as_float(b1 & 0xFFFF0000u);
            const float r2 = kreg[i][2] - __uint_as_float(b2 & 0xFFFF0000u);
            const float r3 = kreg[i][3] - __uint_as_float(b3 & 0xFFFF0000u);
            const unsigned h01 = __builtin_amdgcn_perm(b1, b0, 0x07060302u);
            const unsigned h23 = __builtin_amdgcn_perm(b3, b2, 0x07060302u);
            const unsigned l01 = __builtin_amdgcn_perm(__float_as_uint(r1), __float_as_uint(r0), 0x07060302u);
            const unsigned l23 = __builtin_amdgcn_perm(__float_as_uint(r3), __float_as_uint(r2), 0x07060302u);
            const int off = row * 256 + ((kc4 * 8) ^ ((row & 15) << 4));
            *(uint2*)(Khi + off) = make_uint2(h01, h23);
            *(uint2*)(Klo + off) = make_uint2(l01, l23);
        }
#pragma unroll
        for (int i = 0; i < 4; ++i) {
#pragma unroll
            for (int j = 0; j < 4; ++j) {
                const int d = (vc8 + i * 8) * 4 + j;
                const int off = d * 64 + ((vkv * 2) ^ ((d & 7) << 3));
                const unsigned bb = __float_as_uint(vreg[i][j]);
                *(unsigned short*)(Vhi + off) = (unsigned short)(bb >> 16);
                const float r = vreg[i][j] - __uint_as_float(bb & 0xFFFF0000u);
                *(unsigned short*)(Vlo + off) = (unsigned short)(__float_as_uint(r) >> 16);
            }
        }
    };

    auto mload = [&](int t, f32x4& d0, f32x4& d1) {
        const int kv0 = kv_of(t);
        d0 = *(const f32x4*)(Mrow + kv0 + 4 * g);
        d1 = *(const f32x4*)(Mrow + kv0 + 16 + 4 * g);
    };

    f32x4 o_[8];
#pragma unroll
    for (int nt = 0; nt < 8; ++nt) o_[nt] = 0.f;
    float mrow = -INFINITY, lrow = 0.f;
    f32x4 mA0, mA1, mB0, mB1;

    stage_load(0);
    mload(0, mA0, mA1);
    mload(1, mB0, mB1);
    stage_write();
    __syncthreads();

    auto step = [&](int t, f32x4& m0, f32x4& m1) {
        const bool more = (t + 1 < nstep);
        if (more) stage_load(t + 1);     // global -> regs, written after barrier1

        // ---- S^T = K * Q^T ----
        const char* Khi = slotbase;
        const char* Klo = slotbase + 8192;
        f32x4 sT[2];
        sT[0] = 0.f; sT[1] = 0.f;
        __builtin_amdgcn_s_setprio(1);
#pragma unroll
        for (int c = 0; c < 4; ++c) {
#pragma unroll
            for (int nt = 0; nt < 2; ++nt) {
                const int row = nt * 16 + m16;
                const int off = row * 256 + ((c * 64 + g * 16) ^ ((row & 15) << 4));
                bf16x8 ah = *(const bf16x8*)(Khi + off);
                bf16x8 al = *(const bf16x8*)(Klo + off);
                sT[nt] = MFMA16(ah, qh[c], sT[nt], 0, 0, 0);
                sT[nt] = MFMA16(ah, ql[c], sT[nt], 0, 0, 0);
                sT[nt] = MFMA16(al, qh[c], sT[nt], 0, 0, 0);
            }
        }
        __builtin_amdgcn_s_setprio(0);

        // ---- masked online softmax: lane(g,m16) owns q=m16, kv=nt*16+4g+r ----
        float p[2][4];
        float mx = -INFINITY;
#pragma unroll
        for (int r = 0; r < 4; ++r) {
            p[0][r] = sT[0][r] * m0[r];
            p[1][r] = sT[1][r] * m1[r];
            mx = fmaxf(mx, fmaxf(p[0][r], p[1][r]));
        }
        if (t + 2 < nstep) mload(t + 2, m0, m1);   // refill consumed slot (2-step cover)
        mx = fmaxf(mx, __shfl_xor(mx, 16));
        mx = fmaxf(mx, __shfl_xor(mx, 32));
        const float mn = fmaxf(mrow, mx);
        const float corr = __expf(mrow - mn);
        mrow = mn;
        float ps = 0.f;
#pragma unroll
        for (int nt = 0; nt < 2; ++nt)
#pragma unroll
            for (int r = 0; r < 4; ++r) {
                p[nt][r] = __expf(p[nt][r] - mn);
                ps += p[nt][r];
            }
        ps += __shfl_xor(ps, 16);
        ps += __shfl_xor(ps, 32);
        lrow = lrow * corr + ps;

        f32x4 corrO;
#pragma unroll
        for (int r = 0; r < 4; ++r) corrO[r] = __shfl(corr, 4 * g + r);
#pragma unroll
        for (int nt = 0; nt < 8; ++nt)
#pragma unroll
            for (int r = 0; r < 4; ++r) o_[nt][r] *= corrO[r];

        // ---- P fragments (trunc split, perm-packed): elem e = p[e>>2][e&3] ----
        union { unsigned u[4]; bf16x8 v; } PH, PL;
#pragma unroll
        for (int e = 0; e < 8; e += 2) {
            const float x0 = p[e >> 2][e & 3];
            const float x1 = p[(e + 1) >> 2][(e + 1) & 3];
            const unsigned c0 = __float_as_uint(x0), c1 = __float_as_uint(x1);
            PH.u[e >> 1] = __builtin_amdgcn_perm(c1, c0, 0x07060302u);
            const float r0 = x0 - __uint_as_float(c0 & 0xFFFF0000u);
            const float r1 = x1 - __uint_as_float(c1 & 0xFFFF0000u);
            PL.u[e >> 1] = __builtin_amdgcn_perm(__float_as_uint(r1), __float_as_uint(r0), 0x07060302u);
        }
        const bf16x8 ph = PH.v, pl = PL.v;

        // ---- O += P V : B-frag from vT, kv cols {4g..4g+3, 16+4g..+3} ----
        const char* Vhi = slotbase + 16384;
        const char* Vlo = slotbase + 24576;
        __builtin_amdgcn_s_setprio(1);
#pragma unroll
        for (int nt = 0; nt < 8; ++nt) {
            const int d = nt * 16 + m16;
            const int sw = (d & 7) << 3;
            const int off1 = d * 64 + ((g * 8) ^ sw);
            const int off2 = d * 64 + ((32 + g * 8) ^ sw);
            short4v h1 = *(const short4v*)(Vhi + off1);
            short4v h2 = *(const short4v*)(Vhi + off2);
            short4v l1 = *(const short4v*)(Vlo + off1);
            short4v l2 = *(const short4v*)(Vlo + off2);
            bf16x8 vh = __builtin_shufflevector(h1, h2, 0, 1, 2, 3, 4, 5, 6, 7);
            bf16x8 vl = __builtin_shufflevector(l1, l2, 0, 1, 2, 3, 4, 5, 6, 7);
            o_[nt] = MFMA16(ph, vh, o_[nt], 0, 0, 0);
            o_[nt] = MFMA16(ph, vl, o_[nt], 0, 0, 0);
            o_[nt] = MFMA16(pl, vh, o_[nt], 0, 0, 0);
        }
        __builtin_amdgcn_s_setprio(0);

        __syncthreads();                 // all reads of current tile done
        if (more) stage_write();         // overwrite single buffer
        __syncthreads();                 // writes visible
    };

    for (int t = 0; t < nstep; t += 2) {
        step(t, mA0, mA1);
        step(t + 1, mB0, mB1);
    }

    // ---- in-block flash merge of the two kv groups ----
    if (g2 == 1) {
        char* ob = smem + wq * 8448;
#pragma unroll
        for (int nt = 0; nt < 8; ++nt)
#pragma unroll
            for (int r = 0; r < 4; ++r)
                *(float*)(ob + (4 * g + r) * 528 + (nt * 16 + m16) * 4) = o_[nt][r];
        if (g == 0)
            *(float2*)(smem + 33792 + wq * 128 + m16 * 8) = make_float2(mrow, lrow);
    }
    __syncthreads();
    if (g2 == 0) {
        const float2 ml1 = *(const float2*)(smem + 33792 + wq * 128 + m16 * 8);
        const float ms = fmaxf(mrow, ml1.x);
        const float e0 = __expf(mrow - ms);
        const float e1 = __expf(ml1.x - ms);
        const float lcomb = lrow * e0 + ml1.y * e1;
        const float inv = 1.f / lcomb;
        const float a0 = e0 * inv, a1 = e1 * inv;
        if (nkvh == 2 && g == 0)
            MLout[(size_t)kvh * ROWS + rowglobal + m16] = make_float2(ms, lcomb);
        f32x4 a0r, a1r;
#pragma unroll
        for (int r = 0; r < 4; ++r) {
            a0r[r] = __shfl(a0, 4 * g + r);
            a1r[r] = __shfl(a1, 4 * g + r);
        }
        const char* ob = smem + wq * 8448;
#pragma unroll
        for (int nt = 0; nt < 8; ++nt)
#pragma unroll
            for (int r = 0; r < 4; ++r) {
                const int d = nt * 16 + m16;
                const float o1 = *(const float*)(ob + (4 * g + r) * 528 + d * 4);
                Orow[(size_t)(4 * g + r) * DH + d] = o_[nt][r] * a0r[r] + o1 * a1r[r];
            }
    }
}

// Combine the 2 cross-block partials: O = (w0*O0 + w1*O1)/(w0+w1), wi = e^(mi-ms)*li
__global__ __launch_bounds__(256) void merge_kernel(
    const float* __restrict__ Op, const float2* __restrict__ ml, float* __restrict__ O)
{
    const int fi = blockIdx.x * 256 + threadIdx.x;   // float4 index, 32 per row
    const int row = fi >> 5, c = fi & 31;
    const float2 a = ml[row];
    const float2 bml = ml[row + ROWS];
    const float ms = fmaxf(a.x, bml.x);
    const float w0 = __expf(a.x - ms) * a.y;
    const float w1 = __expf(bml.x - ms) * bml.y;
    const float inv = 1.f / (w0 + w1);
    const float s0 = w0 * inv, s1 = w1 * inv;
    const float4 o0 = *(const float4*)(Op + ((size_t)row << 7) + (c << 2));
    const float4 o1 = *(const float4*)(Op + ((size_t)(row + ROWS) << 7) + (c << 2));
    float4 o;
    o.x = s0 * o0.x + s1 * o1.x;
    o.y = s0 * o0.y + s1 * o1.y;
    o.z = s0 * o0.z + s1 * o1.z;
    o.w = s0 * o0.w + s1 * o1.w;
    *(float4*)(O + ((size_t)row << 7) + (c << 2)) = o;
}

extern "C" void kernel_launch(void* const* d_in, const int* in_sizes, int n_in,
                              void* d_out, int out_size, void* d_ws, size_t ws_size,
                              hipStream_t stream) {
    (void)in_sizes; (void)n_in; (void)out_size;
    const float* q = (const float*)d_in[0];
    const float* k = (const float*)d_in[1];
    const float* v = (const float*)d_in[2];
    const float* m = (const float*)d_in[3];
    float* o = (float*)d_out;
    if (ws_size >= WS_NEED) {
        float* opart = (float*)d_ws;
        float2* ml = (float2*)((char*)d_ws + OPART_BYTES);
        fattn_kernel<<<dim3(512), dim3(512), 0, stream>>>(q, k, v, m, opart, ml, 2);
        merge_kernel<<<dim3(2048), dim3(256), 0, stream>>>(opart, ml, o);
    } else {
        fattn_kernel<<<dim3(256), dim3(512), 0, stream>>>(q, k, v, m, o, nullptr, 1);
    }
}

// Round 6
// 345.795 us; speedup vs baseline: 1.3605x; 1.3605x over previous
//
#include <hip/hip_runtime.h>
#include <math.h>

// Masked attention fwd, B=8, Sq=Sk=2048, D=128, fp32 in/out.
// Flash-attention, swapped QK^T (S^T = K*Q^T) so P stays in-lane for PV.
// bf16 hi/lo split MFMA (3 mfma per product => ~fp32 accuracy).
// R5: 256-thread blocks (4 waves), launch_bounds(256,3) -> 3 blocks/CU,
// 12 waves/CU, VGPR cap ~170 (no spills). 4-way cross-block KV split,
// partials merged by a second kernel.

typedef short bf16x8 __attribute__((ext_vector_type(8)));
typedef short short4v __attribute__((ext_vector_type(4)));
typedef float f32x4 __attribute__((ext_vector_type(4)));

#define MFMA16 __builtin_amdgcn_mfma_f32_16x16x32_bf16

namespace {
constexpr int SKn = 2048, DH = 128;
constexpr int QB = 64;
constexpr int ROWS = 8 * 2048;                          // 16384 q rows total
constexpr size_t OPART4 = 4ull * ROWS * DH * 4;         // 33.5 MiB
constexpr size_t ML4 = 4ull * ROWS * 8;                 // 512 KiB
constexpr size_t WS_NEED4 = OPART4 + ML4;
constexpr size_t OPART2 = 2ull * ROWS * DH * 4;
constexpr size_t ML2 = 2ull * ROWS * 8;
constexpr size_t WS_NEED2 = OPART2 + ML2;

__device__ __forceinline__ unsigned short f2bf(float f) {   // RNE (prologue only)
    union { float f; unsigned u; } x; x.f = f;
    unsigned r = x.u + 0x7FFFu + ((x.u >> 16) & 1u);
    return (unsigned short)(r >> 16);
}
__device__ __forceinline__ float bf2f(unsigned short h) {
    union { unsigned u; float f; } x; x.u = ((unsigned)h) << 16;
    return x.f;
}
}  // namespace

// LDS map (single 32KB buffer per block):
//   Khi +0      [32 kv][128 d] bf16, 256B rows, swz: col ^ ((kv&15)<<4)
//   Klo +8192
//   Vhi +16384  [128 d][32 kv] bf16, 64B rows,  swz: col ^ ((d&7)<<3)
//   Vlo +24576
__global__ __launch_bounds__(256, 3) void fattn_kernel(
    const float* __restrict__ Q, const float* __restrict__ K,
    const float* __restrict__ V, const float* __restrict__ M,
    float* __restrict__ Oout, float2* __restrict__ MLout, const int nkvh)
{
    __shared__ __align__(16) char smem[32768];
    const int bid = blockIdx.x;
    const int b  = bid & 7;          // batch per XCD for K/V L2 locality
    const int rest = bid >> 3;
    const int kvh = rest % nkvh;     // cross-block kv slice
    const int qt = rest / nkvh;
    const int kvspan = SKn / nkvh;
    const int nstep = kvspan / 32;   // nkvh=4 -> 16, 2 -> 32, 1 -> 64
    const int tid = threadIdx.x;
    const int lane = tid & 63;
    const int wq = tid >> 6;         // wave 0..3 = q sub-tile, rows wq*16..+15
    const int m16 = lane & 15;
    const int g = lane >> 4;

    const int rowglobal = b * 2048 + qt * QB + wq * 16;
    const float* Qw = Q + (size_t)rowglobal * DH;
    const float* Kb = K + (size_t)b * SKn * DH;
    const float* Vb = V + (size_t)b * SKn * DH;
    const float* Mrow = M + (size_t)rowglobal * SKn + (size_t)m16 * SKn;
    float* Orow = Oout + ((size_t)kvh * ROWS + rowglobal) * DH;

    // ---- Q fragments (B-operand of S^T: lane(g,m16) holds Q[m16][c*32+g*8+e]) ----
    bf16x8 qh[4], ql[4];
#pragma unroll
    for (int c = 0; c < 4; ++c) {
        const float* qp = Qw + m16 * DH + c * 32 + g * 8;
        f32x4 a0 = *(const f32x4*)qp;
        f32x4 a1 = *(const f32x4*)(qp + 4);
#pragma unroll
        for (int j = 0; j < 8; ++j) {
            float x = (j < 4) ? a0[j] : a1[j - 4];
            unsigned short h = f2bf(x);
            qh[c][j] = (short)h;
            ql[c][j] = (short)f2bf(x - bf2f(h));
        }
    }

    f32x4 kreg[4], vreg[4];
    const int krow = tid >> 5, kc4 = tid & 31;   // K stage: coalesced
    const int vkv = tid & 31,  vc8 = tid >> 5;   // V stage: row-strided

    auto kv_of = [&](int t) { return kvh * kvspan + t * 32; };

    auto stage_load = [&](int t) {
        const int kv0 = kv_of(t);
#pragma unroll
        for (int i = 0; i < 4; ++i)
            kreg[i] = *(const f32x4*)(Kb + (size_t)(kv0 + i * 8 + krow) * DH + kc4 * 4);
#pragma unroll
        for (int i = 0; i < 4; ++i)
            vreg[i] = *(const f32x4*)(Vb + (size_t)(kv0 + vkv) * DH + (vc8 + i * 8) * 4);
    };

    // truncation hi/lo split + v_perm packing (hot path)
    auto stage_write = [&]() {
        char* Khi = smem;
        char* Klo = smem + 8192;
        char* Vhi = smem + 16384;
        char* Vlo = smem + 24576;
#pragma unroll
        for (int i = 0; i < 4; ++i) {
            const int row = i * 8 + krow;
            const unsigned b0 = __float_as_uint(kreg[i][0]);
            const unsigned b1 = __float_as_uint(kreg[i][1]);
            const unsigned b2 = __float_as_uint(kreg[i][2]);
            const unsigned b3 = __float_as_uint(kreg[i][3]);
            const float r0 = kreg[i][0] - __uint_as_float(b0 & 0xFFFF0000u);
            const float r1 = kreg[i][1] - __uint_as_float(b1 & 0xFFFF0000u);
            const float r2 = kreg[i][2] - __uint_as_float(b2 & 0xFFFF0000u);
            const float r3 = kreg[i][3] - __uint_as_float(b3 & 0xFFFF0000u);
            const unsigned h01 = __builtin_amdgcn_perm(b1, b0, 0x07060302u);
            const unsigned h23 = __builtin_amdgcn_perm(b3, b2, 0x07060302u);
            const unsigned l01 = __builtin_amdgcn_perm(__float_as_uint(r1), __float_as_uint(r0), 0x07060302u);
            const unsigned l23 = __builtin_amdgcn_perm(__float_as_uint(r3), __float_as_uint(r2), 0x07060302u);
            const int off = row * 256 + ((kc4 * 8) ^ ((row & 15) << 4));
            *(uint2*)(Khi + off) = make_uint2(h01, h23);
            *(uint2*)(Klo + off) = make_uint2(l01, l23);
        }
#pragma unroll
        for (int i = 0; i < 4; ++i) {
#pragma unroll
            for (int j = 0; j < 4; ++j) {
                const int d = (vc8 + i * 8) * 4 + j;
                const int off = d * 64 + ((vkv * 2) ^ ((d & 7) << 3));
                const unsigned bb = __float_as_uint(vreg[i][j]);
                *(unsigned short*)(Vhi + off) = (unsigned short)(bb >> 16);
                const float r = vreg[i][j] - __uint_as_float(bb & 0xFFFF0000u);
                *(unsigned short*)(Vlo + off) = (unsigned short)(__float_as_uint(r) >> 16);
            }
        }
    };

    auto mload = [&](int t, f32x4& d0, f32x4& d1) {
        const int kv0 = kv_of(t);
        d0 = *(const f32x4*)(Mrow + kv0 + 4 * g);
        d1 = *(const f32x4*)(Mrow + kv0 + 16 + 4 * g);
    };

    f32x4 o_[8];
#pragma unroll
    for (int nt = 0; nt < 8; ++nt) o_[nt] = 0.f;
    float mrow = -INFINITY, lrow = 0.f;
    f32x4 mA0, mA1, mB0, mB1;

    stage_load(0);
    mload(0, mA0, mA1);
    mload(1, mB0, mB1);
    stage_write();
    __syncthreads();

    auto step = [&](int t, f32x4& m0, f32x4& m1) {
        const bool more = (t + 1 < nstep);
        if (more) stage_load(t + 1);     // global -> regs, written after barrier1

        // ---- S^T = K * Q^T ----
        const char* Khi = smem;
        const char* Klo = smem + 8192;
        f32x4 sT[2];
        sT[0] = 0.f; sT[1] = 0.f;
        __builtin_amdgcn_s_setprio(1);
#pragma unroll
        for (int c = 0; c < 4; ++c) {
#pragma unroll
            for (int nt = 0; nt < 2; ++nt) {
                const int row = nt * 16 + m16;
                const int off = row * 256 + ((c * 64 + g * 16) ^ ((row & 15) << 4));
                bf16x8 ah = *(const bf16x8*)(Khi + off);
                bf16x8 al = *(const bf16x8*)(Klo + off);
                sT[nt] = MFMA16(ah, qh[c], sT[nt], 0, 0, 0);
                sT[nt] = MFMA16(ah, ql[c], sT[nt], 0, 0, 0);
                sT[nt] = MFMA16(al, qh[c], sT[nt], 0, 0, 0);
            }
        }
        __builtin_amdgcn_s_setprio(0);

        // ---- masked online softmax: lane(g,m16) owns q=m16, kv=nt*16+4g+r ----
        float p[2][4];
        float mx = -INFINITY;
#pragma unroll
        for (int r = 0; r < 4; ++r) {
            p[0][r] = sT[0][r] * m0[r];
            p[1][r] = sT[1][r] * m1[r];
            mx = fmaxf(mx, fmaxf(p[0][r], p[1][r]));
        }
        if (t + 2 < nstep) mload(t + 2, m0, m1);   // refill consumed slot
        mx = fmaxf(mx, __shfl_xor(mx, 16));
        mx = fmaxf(mx, __shfl_xor(mx, 32));
        const float mn = fmaxf(mrow, mx);
        const float corr = __expf(mrow - mn);
        mrow = mn;
        float ps = 0.f;
#pragma unroll
        for (int nt = 0; nt < 2; ++nt)
#pragma unroll
            for (int r = 0; r < 4; ++r) {
                p[nt][r] = __expf(p[nt][r] - mn);
                ps += p[nt][r];
            }
        ps += __shfl_xor(ps, 16);
        ps += __shfl_xor(ps, 32);
        lrow = lrow * corr + ps;

        f32x4 corrO;
#pragma unroll
        for (int r = 0; r < 4; ++r) corrO[r] = __shfl(corr, 4 * g + r);
#pragma unroll
        for (int nt = 0; nt < 8; ++nt)
#pragma unroll
            for (int r = 0; r < 4; ++r) o_[nt][r] *= corrO[r];

        // ---- P fragments (trunc split, perm-packed): elem e = p[e>>2][e&3] ----
        union { unsigned u[4]; bf16x8 v; } PH, PL;
#pragma unroll
        for (int e = 0; e < 8; e += 2) {
            const float x0 = p[e >> 2][e & 3];
            const float x1 = p[(e + 1) >> 2][(e + 1) & 3];
            const unsigned c0 = __float_as_uint(x0), c1 = __float_as_uint(x1);
            PH.u[e >> 1] = __builtin_amdgcn_perm(c1, c0, 0x07060302u);
            const float r0 = x0 - __uint_as_float(c0 & 0xFFFF0000u);
            const float r1 = x1 - __uint_as_float(c1 & 0xFFFF0000u);
            PL.u[e >> 1] = __builtin_amdgcn_perm(__float_as_uint(r1), __float_as_uint(r0), 0x07060302u);
        }
        const bf16x8 ph = PH.v, pl = PL.v;

        // ---- O += P V : B-frag from vT, kv cols {4g..4g+3, 16+4g..+3} ----
        const char* Vhi = smem + 16384;
        const char* Vlo = smem + 24576;
        __builtin_amdgcn_s_setprio(1);
#pragma unroll
        for (int nt = 0; nt < 8; ++nt) {
            const int d = nt * 16 + m16;
            const int sw = (d & 7) << 3;
            const int off1 = d * 64 + ((g * 8) ^ sw);
            const int off2 = d * 64 + ((32 + g * 8) ^ sw);
            short4v h1 = *(const short4v*)(Vhi + off1);
            short4v h2 = *(const short4v*)(Vhi + off2);
            short4v l1 = *(const short4v*)(Vlo + off1);
            short4v l2 = *(const short4v*)(Vlo + off2);
            bf16x8 vh = __builtin_shufflevector(h1, h2, 0, 1, 2, 3, 4, 5, 6, 7);
            bf16x8 vl = __builtin_shufflevector(l1, l2, 0, 1, 2, 3, 4, 5, 6, 7);
            o_[nt] = MFMA16(ph, vh, o_[nt], 0, 0, 0);
            o_[nt] = MFMA16(ph, vl, o_[nt], 0, 0, 0);
            o_[nt] = MFMA16(pl, vh, o_[nt], 0, 0, 0);
        }
        __builtin_amdgcn_s_setprio(0);

        __syncthreads();                 // all reads of current tile done
        if (more) stage_write();         // overwrite single buffer
        __syncthreads();                 // writes visible
    };

    for (int t = 0; t < nstep; t += 2) {
        step(t, mA0, mA1);
        step(t + 1, mB0, mB1);
    }

    // ---- epilogue: per-partial normalize + store; (m,l) for cross-block merge ----
    if (nkvh > 1 && g == 0)
        MLout[(size_t)kvh * ROWS + rowglobal + m16] = make_float2(mrow, lrow);
    const float inv = 1.f / lrow;
    f32x4 invr;
#pragma unroll
    for (int r = 0; r < 4; ++r) invr[r] = __shfl(inv, 4 * g + r);
#pragma unroll
    for (int nt = 0; nt < 8; ++nt)
#pragma unroll
        for (int r = 0; r < 4; ++r)
            Orow[(size_t)(4 * g + r) * DH + (nt * 16 + m16)] = o_[nt][r] * invr[r];
}

// Combine npart partials: O = sum_p w_p * O_p / sum_p w_p, w_p = e^(m_p-ms) * l_p
__global__ __launch_bounds__(256) void merge_kernel(
    const float* __restrict__ Op, const float2* __restrict__ ml,
    float* __restrict__ O, const int npart)
{
    const int fi = blockIdx.x * 256 + threadIdx.x;   // float4 index, 32 per row
    const int row = fi >> 5, c = fi & 31;
    float ms = -INFINITY;
    for (int p = 0; p < npart; ++p) ms = fmaxf(ms, ml[(size_t)p * ROWS + row].x);
    float4 acc = make_float4(0.f, 0.f, 0.f, 0.f);
    float wsum = 0.f;
    for (int p = 0; p < npart; ++p) {
        const float2 a = ml[(size_t)p * ROWS + row];
        const float wp = __expf(a.x - ms) * a.y;
        wsum += wp;
        const float4 o = *(const float4*)(Op + (((size_t)p * ROWS + row) << 7) + (c << 2));
        acc.x += wp * o.x; acc.y += wp * o.y; acc.z += wp * o.z; acc.w += wp * o.w;
    }
    const float inv = 1.f / wsum;
    float4 o;
    o.x = acc.x * inv; o.y = acc.y * inv; o.z = acc.z * inv; o.w = acc.w * inv;
    *(float4*)(O + ((size_t)row << 7) + (c << 2)) = o;
}

extern "C" void kernel_launch(void* const* d_in, const int* in_sizes, int n_in,
                              void* d_out, int out_size, void* d_ws, size_t ws_size,
                              hipStream_t stream) {
    (void)in_sizes; (void)n_in; (void)out_size;
    const float* q = (const float*)d_in[0];
    const float* k = (const float*)d_in[1];
    const float* v = (const float*)d_in[2];
    const float* m = (const float*)d_in[3];
    float* o = (float*)d_out;
    if (ws_size >= WS_NEED4) {
        float* opart = (float*)d_ws;
        float2* ml = (float2*)((char*)d_ws + OPART4);
        fattn_kernel<<<dim3(1024), dim3(256), 0, stream>>>(q, k, v, m, opart, ml, 4);
        merge_kernel<<<dim3(2048), dim3(256), 0, stream>>>(opart, ml, o, 4);
    } else if (ws_size >= WS_NEED2) {
        float* opart = (float*)d_ws;
        float2* ml = (float2*)((char*)d_ws + OPART2);
        fattn_kernel<<<dim3(512), dim3(256), 0, stream>>>(q, k, v, m, opart, ml, 2);
        merge_kernel<<<dim3(2048), dim3(256), 0, stream>>>(opart, ml, o, 2);
    } else {
        fattn_kernel<<<dim3(256), dim3(256), 0, stream>>>(q, k, v, m, o, nullptr, 1);
    }
}

// Round 7
// 336.512 us; speedup vs baseline: 1.3981x; 1.0276x over previous
//
#include <hip/hip_runtime.h>
#include <math.h>

// Masked attention fwd, B=8, Sq=Sk=2048, D=128, fp32 in/out.
// Flash-attention, swapped QK^T (S^T = K*Q^T) so P stays in-lane for PV.
// QK^T: bf16 hi/lo split (3 mfma). PV: P hi/lo x V hi (2 mfma).
// R6: 256-thread blocks, launch_bounds(256,3), double-buffered 48KB LDS,
// ONE raw barrier per step (lgkmcnt only, no vmcnt drain -> prefetch
// survives barriers). 4-way cross-block KV split + merge kernel.

typedef short bf16x8 __attribute__((ext_vector_type(8)));
typedef short short4v __attribute__((ext_vector_type(4)));
typedef float f32x4 __attribute__((ext_vector_type(4)));

#define MFMA16 __builtin_amdgcn_mfma_f32_16x16x32_bf16
// write-visibility barrier: drain own LDS writes, then block barrier.
// memory clobber keeps all LDS/global ops on their side of the fence.
#define BARRIER_SYNC() asm volatile("s_waitcnt lgkmcnt(0)\n\ts_barrier" ::: "memory")

namespace {
constexpr int SKn = 2048, DH = 128;
constexpr int QB = 64;
constexpr int ROWS = 8 * 2048;                          // 16384 q rows total
constexpr size_t OPART4 = 4ull * ROWS * DH * 4;         // 33.5 MiB
constexpr size_t ML4 = 4ull * ROWS * 8;                 // 512 KiB
constexpr size_t WS_NEED4 = OPART4 + ML4;
constexpr size_t OPART2 = 2ull * ROWS * DH * 4;
constexpr size_t ML2 = 2ull * ROWS * 8;
constexpr size_t WS_NEED2 = OPART2 + ML2;

__device__ __forceinline__ unsigned short f2bf(float f) {   // RNE (prologue only)
    union { float f; unsigned u; } x; x.f = f;
    unsigned r = x.u + 0x7FFFu + ((x.u >> 16) & 1u);
    return (unsigned short)(r >> 16);
}
__device__ __forceinline__ float bf2f(unsigned short h) {
    union { unsigned u; float f; } x; x.u = ((unsigned)h) << 16;
    return x.f;
}
}  // namespace

// LDS map, buffer b at b*24576 (2 buffers = 48 KB):
//   Khi +0      [32 kv][128 d] bf16, 256B rows, swz: col ^ ((kv&15)<<4)
//   Klo +8192
//   Vhi +16384  [128 d][32 kv] bf16, 64B rows,  swz: col ^ ((d&7)<<3)
__global__ __launch_bounds__(256, 3) void fattn_kernel(
    const float* __restrict__ Q, const float* __restrict__ K,
    const float* __restrict__ V, const float* __restrict__ M,
    float* __restrict__ Oout, float2* __restrict__ MLout, const int nkvh)
{
    __shared__ __align__(16) char smem[49152];
    const int bid = blockIdx.x;
    const int b  = bid & 7;          // batch per XCD for K/V L2 locality
    const int rest = bid >> 3;
    const int kvh = rest % nkvh;     // cross-block kv slice
    const int qt = rest / nkvh;
    const int kvspan = SKn / nkvh;
    const int nstep = kvspan / 32;   // nkvh=4 -> 16
    const int tid = threadIdx.x;
    const int lane = tid & 63;
    const int wq = tid >> 6;         // wave 0..3 = q sub-tile, rows wq*16..+15
    const int m16 = lane & 15;
    const int g = lane >> 4;

    const int rowglobal = b * 2048 + qt * QB + wq * 16;
    const float* Qw = Q + (size_t)rowglobal * DH;
    const float* Kb = K + (size_t)b * SKn * DH;
    const float* Vb = V + (size_t)b * SKn * DH;
    const float* Mrow = M + (size_t)rowglobal * SKn + (size_t)m16 * SKn;
    float* Orow = Oout + ((size_t)kvh * ROWS + rowglobal) * DH;

    // ---- Q fragments (B-operand of S^T: lane(g,m16) holds Q[m16][c*32+g*8+e]) ----
    bf16x8 qh[4], ql[4];
#pragma unroll
    for (int c = 0; c < 4; ++c) {
        const float* qp = Qw + m16 * DH + c * 32 + g * 8;
        f32x4 a0 = *(const f32x4*)qp;
        f32x4 a1 = *(const f32x4*)(qp + 4);
#pragma unroll
        for (int j = 0; j < 8; ++j) {
            float x = (j < 4) ? a0[j] : a1[j - 4];
            unsigned short h = f2bf(x);
            qh[c][j] = (short)h;
            ql[c][j] = (short)f2bf(x - bf2f(h));
        }
    }

    f32x4 kreg[4], vreg[4];
    const int krow = tid >> 5, kc4 = tid & 31;   // K stage: coalesced
    const int vkv = tid & 31,  vc8 = tid >> 5;   // V stage: row-strided

    auto kv_of = [&](int t) { return kvh * kvspan + t * 32; };

    auto stage_load = [&](int t) {
        const int kv0 = kv_of(t);
#pragma unroll
        for (int i = 0; i < 4; ++i)
            kreg[i] = *(const f32x4*)(Kb + (size_t)(kv0 + i * 8 + krow) * DH + kc4 * 4);
#pragma unroll
        for (int i = 0; i < 4; ++i)
            vreg[i] = *(const f32x4*)(Vb + (size_t)(kv0 + vkv) * DH + (vc8 + i * 8) * 4);
    };

    // truncation hi/lo split + v_perm packing (hot path); V: hi only
    auto stage_write = [&](int bufsel) {
        char* Khi = smem + bufsel * 24576;
        char* Klo = Khi + 8192;
        char* Vhi = Khi + 16384;
#pragma unroll
        for (int i = 0; i < 4; ++i) {
            const int row = i * 8 + krow;
            const unsigned b0 = __float_as_uint(kreg[i][0]);
            const unsigned b1 = __float_as_uint(kreg[i][1]);
            const unsigned b2 = __float_as_uint(kreg[i][2]);
            const unsigned b3 = __float_as_uint(kreg[i][3]);
            const float r0 = kreg[i][0] - __uint_as_float(b0 & 0xFFFF0000u);
            const float r1 = kreg[i][1] - __uint_as_float(b1 & 0xFFFF0000u);
            const float r2 = kreg[i][2] - __uint_as_float(b2 & 0xFFFF0000u);
            const float r3 = kreg[i][3] - __uint_as_float(b3 & 0xFFFF0000u);
            const unsigned h01 = __builtin_amdgcn_perm(b1, b0, 0x07060302u);
            const unsigned h23 = __builtin_amdgcn_perm(b3, b2, 0x07060302u);
            const unsigned l01 = __builtin_amdgcn_perm(__float_as_uint(r1), __float_as_uint(r0), 0x07060302u);
            const unsigned l23 = __builtin_amdgcn_perm(__float_as_uint(r3), __float_as_uint(r2), 0x07060302u);
            const int off = row * 256 + ((kc4 * 8) ^ ((row & 15) << 4));
            *(uint2*)(Khi + off) = make_uint2(h01, h23);
            *(uint2*)(Klo + off) = make_uint2(l01, l23);
        }
#pragma unroll
        for (int i = 0; i < 4; ++i) {
#pragma unroll
            for (int j = 0; j < 4; ++j) {
                const int d = (vc8 + i * 8) * 4 + j;
                const int off = d * 64 + ((vkv * 2) ^ ((d & 7) << 3));
                *(unsigned short*)(Vhi + off) =
                    (unsigned short)(__float_as_uint(vreg[i][j]) >> 16);
            }
        }
    };

    auto mload = [&](int t, f32x4& d0, f32x4& d1) {
        const int kv0 = kv_of(t);
        d0 = *(const f32x4*)(Mrow + kv0 + 4 * g);
        d1 = *(const f32x4*)(Mrow + kv0 + 16 + 4 * g);
    };

    f32x4 o_[8];
#pragma unroll
    for (int nt = 0; nt < 8; ++nt) o_[nt] = 0.f;
    float mrow = -INFINITY, lrow = 0.f;
    f32x4 mA0, mA1, mB0, mB1;

    stage_load(0);
    mload(0, mA0, mA1);
    mload(1, mB0, mB1);
    stage_write(0);
    BARRIER_SYNC();
    stage_load(1);     // tile 1 in regs, written at end of step 0

    auto step = [&](int t, f32x4& m0, f32x4& m1) {
        const int cur = t & 1;
        const bool more = (t + 1 < nstep);

        // ---- S^T = K * Q^T  (buf cur) ----
        const char* Khi = smem + cur * 24576;
        const char* Klo = Khi + 8192;
        f32x4 sT[2];
        sT[0] = 0.f; sT[1] = 0.f;
        __builtin_amdgcn_s_setprio(1);
#pragma unroll
        for (int c = 0; c < 4; ++c) {
#pragma unroll
            for (int nt = 0; nt < 2; ++nt) {
                const int row = nt * 16 + m16;
                const int off = row * 256 + ((c * 64 + g * 16) ^ ((row & 15) << 4));
                bf16x8 ah = *(const bf16x8*)(Khi + off);
                bf16x8 al = *(const bf16x8*)(Klo + off);
                sT[nt] = MFMA16(ah, qh[c], sT[nt], 0, 0, 0);
                sT[nt] = MFMA16(ah, ql[c], sT[nt], 0, 0, 0);
                sT[nt] = MFMA16(al, qh[c], sT[nt], 0, 0, 0);
            }
        }
        __builtin_amdgcn_s_setprio(0);

        // ---- masked online softmax: lane(g,m16) owns q=m16, kv=nt*16+4g+r ----
        float p[2][4];
        float mx = -INFINITY;
#pragma unroll
        for (int r = 0; r < 4; ++r) {
            p[0][r] = sT[0][r] * m0[r];
            p[1][r] = sT[1][r] * m1[r];
            mx = fmaxf(mx, fmaxf(p[0][r], p[1][r]));
        }
        if (t + 2 < nstep) mload(t + 2, m0, m1);   // refill consumed slot
        mx = fmaxf(mx, __shfl_xor(mx, 16));
        mx = fmaxf(mx, __shfl_xor(mx, 32));
        const float mn = fmaxf(mrow, mx);
        const float corr = __expf(mrow - mn);
        mrow = mn;
        float ps = 0.f;
#pragma unroll
        for (int nt = 0; nt < 2; ++nt)
#pragma unroll
            for (int r = 0; r < 4; ++r) {
                p[nt][r] = __expf(p[nt][r] - mn);
                ps += p[nt][r];
            }
        ps += __shfl_xor(ps, 16);
        ps += __shfl_xor(ps, 32);
        lrow = lrow * corr + ps;

        f32x4 corrO;
#pragma unroll
        for (int r = 0; r < 4; ++r) corrO[r] = __shfl(corr, 4 * g + r);
#pragma unroll
        for (int nt = 0; nt < 8; ++nt)
#pragma unroll
            for (int r = 0; r < 4; ++r) o_[nt][r] *= corrO[r];

        // ---- P fragments (trunc split, perm-packed): elem e = p[e>>2][e&3] ----
        union { unsigned u[4]; bf16x8 v; } PH, PL;
#pragma unroll
        for (int e = 0; e < 8; e += 2) {
            const float x0 = p[e >> 2][e & 3];
            const float x1 = p[(e + 1) >> 2][(e + 1) & 3];
            const unsigned c0 = __float_as_uint(x0), c1 = __float_as_uint(x1);
            PH.u[e >> 1] = __builtin_amdgcn_perm(c1, c0, 0x07060302u);
            const float r0 = x0 - __uint_as_float(c0 & 0xFFFF0000u);
            const float r1 = x1 - __uint_as_float(c1 & 0xFFFF0000u);
            PL.u[e >> 1] = __builtin_amdgcn_perm(__float_as_uint(r1), __float_as_uint(r0), 0x07060302u);
        }
        const bf16x8 ph = PH.v, pl = PL.v;

        // ---- O += P V : B-frag from vT (hi only), kv {4g..+3, 16+4g..+3} ----
        const char* Vhi = Khi + 16384;
        __builtin_amdgcn_s_setprio(1);
#pragma unroll
        for (int nt = 0; nt < 8; ++nt) {
            const int d = nt * 16 + m16;
            const int sw = (d & 7) << 3;
            short4v h1 = *(const short4v*)(Vhi + d * 64 + ((g * 8) ^ sw));
            short4v h2 = *(const short4v*)(Vhi + d * 64 + ((32 + g * 8) ^ sw));
            bf16x8 vh = __builtin_shufflevector(h1, h2, 0, 1, 2, 3, 4, 5, 6, 7);
            o_[nt] = MFMA16(ph, vh, o_[nt], 0, 0, 0);
            o_[nt] = MFMA16(pl, vh, o_[nt], 0, 0, 0);
        }
        __builtin_amdgcn_s_setprio(0);

        // ---- stage tile t+1 into buf cur^1 (was fully consumed at step t-1);
        //      kreg/vreg loaded at end of step t-1 -> ~full step of vmcnt cover ----
        if (more) {
            stage_write(cur ^ 1);
            BARRIER_SYNC();              // lgkmcnt(0) + s_barrier, NO vmcnt drain
            if (t + 2 < nstep) stage_load(t + 2);
        }
    };

    for (int t = 0; t < nstep; t += 2) {
        step(t, mA0, mA1);
        step(t + 1, mB0, mB1);
    }

    // ---- epilogue: per-partial normalize + store; (m,l) for cross-block merge ----
    if (nkvh > 1 && g == 0)
        MLout[(size_t)kvh * ROWS + rowglobal + m16] = make_float2(mrow, lrow);
    const float inv = 1.f / lrow;
    f32x4 invr;
#pragma unroll
    for (int r = 0; r < 4; ++r) invr[r] = __shfl(inv, 4 * g + r);
#pragma unroll
    for (int nt = 0; nt < 8; ++nt)
#pragma unroll
        for (int r = 0; r < 4; ++r)
            Orow[(size_t)(4 * g + r) * DH + (nt * 16 + m16)] = o_[nt][r] * invr[r];
}

// Combine npart partials: O = sum_p w_p * O_p / sum_p w_p, w_p = e^(m_p-ms) * l_p
__global__ __launch_bounds__(256) void merge_kernel(
    const float* __restrict__ Op, const float2* __restrict__ ml,
    float* __restrict__ O, const int npart)
{
    const int fi = blockIdx.x * 256 + threadIdx.x;   // float4 index, 32 per row
    const int row = fi >> 5, c = fi & 31;
    float ms = -INFINITY;
    for (int p = 0; p < npart; ++p) ms = fmaxf(ms, ml[(size_t)p * ROWS + row].x);
    float4 acc = make_float4(0.f, 0.f, 0.f, 0.f);
    float wsum = 0.f;
    for (int p = 0; p < npart; ++p) {
        const float2 a = ml[(size_t)p * ROWS + row];
        const float wp = __expf(a.x - ms) * a.y;
        wsum += wp;
        const float4 o = *(const float4*)(Op + (((size_t)p * ROWS + row) << 7) + (c << 2));
        acc.x += wp * o.x; acc.y += wp * o.y; acc.z += wp * o.z; acc.w += wp * o.w;
    }
    const float inv = 1.f / wsum;
    float4 o;
    o.x = acc.x * inv; o.y = acc.y * inv; o.z = acc.z * inv; o.w = acc.w * inv;
    *(float4*)(O + ((size_t)row << 7) + (c << 2)) = o;
}

extern "C" void kernel_launch(void* const* d_in, const int* in_sizes, int n_in,
                              void* d_out, int out_size, void* d_ws, size_t ws_size,
                              hipStream_t stream) {
    (void)in_sizes; (void)n_in; (void)out_size;
    const float* q = (const float*)d_in[0];
    const float* k = (const float*)d_in[1];
    const float* v = (const float*)d_in[2];
    const float* m = (const float*)d_in[3];
    float* o = (float*)d_out;
    if (ws_size >= WS_NEED4) {
        float* opart = (float*)d_ws;
        float2* ml = (float2*)((char*)d_ws + OPART4);
        fattn_kernel<<<dim3(1024), dim3(256), 0, stream>>>(q, k, v, m, opart, ml, 4);
        merge_kernel<<<dim3(2048), dim3(256), 0, stream>>>(opart, ml, o, 4);
    } else if (ws_size >= WS_NEED2) {
        float* opart = (float*)d_ws;
        float2* ml = (float2*)((char*)d_ws + OPART2);
        fattn_kernel<<<dim3(512), dim3(256), 0, stream>>>(q, k, v, m, opart, ml, 2);
        merge_kernel<<<dim3(2048), dim3(256), 0, stream>>>(opart, ml, o, 2);
    } else {
        fattn_kernel<<<dim3(256), dim3(256), 0, stream>>>(q, k, v, m, o, nullptr, 1);
    }
}